// Round 5
// baseline (361.295 us; speedup 1.0000x reference)
//
#include <hip/hip_runtime.h>
#include <math.h>

#define MTOT 9216
#define A_ 36
#define D0_ 64
#define EDGE_ 32
#define RBF_ 16
#define KNN 24
#define QIN_ 67    // D0 + KC
#define EPS_ 1e-5f

// ---- prep: state passthrough copy + pact build + xyz passthrough (fused) ----
__global__ void k_prep(const int* __restrict__ seq, const float* __restrict__ xyz,
                       const int* __restrict__ aamask,
                       const float4* __restrict__ state4, float4* __restrict__ out_state4,
                       float4* __restrict__ pact, float* __restrict__ out_xyz,
                       int* __restrict__ cnt) {
    int t = blockIdx.x * blockDim.x + threadIdx.x;
    if (t < MTOT * D0_ / 4) out_state4[t] = state4[t];
    if (t < MTOT) {
        int r = t / A_;
        int a = t - r * A_;
        int mk = (aamask[seq[r] * A_ + a] != 0);
        float x0 = xyz[t * 3 + 0], x1 = xyz[t * 3 + 1], x2 = xyz[t * 3 + 2];
        out_xyz[t * 3 + 0] = x0;
        out_xyz[t * 3 + 1] = x1;
        out_xyz[t * 3 + 2] = x2;
        if (mk) {
            int p = atomicAdd(cnt, 1);   // compiler wave-aggregates
            pact[p] = make_float4(x0, x1, x2, __int_as_float(t));
        }
    }
}

// ------- exact top-24, wave-per-atom, ballot histogram, 8 waves/WG --------
#define WPB 8
#define CAPN 256

__global__ __launch_bounds__(512) void k_nbr(const float4* __restrict__ pact,
                                             const int* __restrict__ cnt,
                                             int* __restrict__ idx) {
    __shared__ uint2 s_cand[WPB][CAPN];   // 16 KB, per-wave slices

    const int nact = *cnt;
    const int lane = threadIdx.x & 63;
    const int wv = threadIdx.x >> 6;
    const int slot = blockIdx.x * WPB + wv;
    if (slot >= nact) return;             // wave-uniform; no block barriers anywhere

    const float4 pq = pact[slot];
    const int ia = __float_as_int(pq.w);
    const unsigned long long lmask = (1ULL << lane) - 1ULL;

    // ---- pass A: cumulative histogram at 16 coarse thresholds (bins 2b+1) ----
    unsigned cum[16];
    #pragma unroll
    for (int b = 0; b < 16; ++b) cum[b] = 0u;

    for (int base = 0; base < nact; base += 128) {
        int c0 = base + lane, c1 = c0 + 64;          // pact padded: OOB-safe
        float4 p0 = pact[c0];
        float4 p1 = pact[c1];
        int j0 = __float_as_int(p0.w), j1 = __float_as_int(p1.w);
        float dx0 = p0.x - pq.x, dy0 = p0.y - pq.y, dz0 = p0.z - pq.z;
        float dx1 = p1.x - pq.x, dy1 = p1.y - pq.y, dz1 = p1.z - pq.z;
        float d20 = dx0 * dx0 + dy0 * dy0 + dz0 * dz0;
        float d21 = dx1 * dx1 + dy1 * dy1 + dz1 * dz1;
        int bb0 = min(max((int)(__float_as_uint(d20) >> 22) - 240, 0), 31);
        int bb1 = min(max((int)(__float_as_uint(d21) >> 22) - 240, 0), 31);
        unsigned bin0 = (c0 < nact && j0 != ia) ? (unsigned)bb0 : 1000u;
        unsigned bin1 = (c1 < nact && j1 != ia) ? (unsigned)bb1 : 1000u;
        #pragma unroll
        for (int b = 0; b < 16; ++b) {
            unsigned t = (unsigned)(2 * b + 1);
            cum[b] += (unsigned)__popcll(__ballot(bin0 <= t))
                    + (unsigned)__popcll(__ballot(bin1 <= t));
        }
    }
    int bsel = 15;
    #pragma unroll
    for (int b = 15; b >= 0; --b) if (cum[b] >= KNN) bsel = b;
    const unsigned limit = (unsigned)(242 + 2 * bsel) << 22;

    // ---- pass B: ballot-compacted candidate collection (superset of top-24) ----
    int nsel = 0;
    for (int base = 0; base < nact; base += 128) {
        int c0 = base + lane, c1 = c0 + 64;
        float4 p0 = pact[c0];
        float4 p1 = pact[c1];
        int j0 = __float_as_int(p0.w), j1 = __float_as_int(p1.w);
        float dx0 = p0.x - pq.x, dy0 = p0.y - pq.y, dz0 = p0.z - pq.z;
        float dx1 = p1.x - pq.x, dy1 = p1.y - pq.y, dz1 = p1.z - pq.z;
        unsigned bt0 = __float_as_uint(dx0 * dx0 + dy0 * dy0 + dz0 * dz0);
        unsigned bt1 = __float_as_uint(dx1 * dx1 + dy1 * dy1 + dz1 * dz1);
        bool sel0 = (c0 < nact) && (j0 != ia) && (bt0 < limit);
        bool sel1 = (c1 < nact) && (j1 != ia) && (bt1 < limit);
        unsigned long long m0 = __ballot(sel0);
        int pos0 = nsel + (int)__popcll(m0 & lmask);
        if (sel0 && pos0 < CAPN) s_cand[wv][pos0] = make_uint2(bt0, (unsigned)j0);
        nsel += (int)__popcll(m0);
        unsigned long long m1 = __ballot(sel1);
        int pos1 = nsel + (int)__popcll(m1 & lmask);
        if (sel1 && pos1 < CAPN) s_cand[wv][pos1] = make_uint2(bt1, (unsigned)j1);
        nsel += (int)__popcll(m1);
    }
    __builtin_amdgcn_wave_barrier();

    // ---- exact rank select ((d2, j) lex == lax.top_k tie-break) ----
    int n = min(nsel, CAPN);
    for (int c = lane; c < n; c += 64) {
        uint2 my = s_cand[wv][c];
        int rank = 0;
        for (int c2 = 0; c2 < n; ++c2) {
            uint2 o = s_cand[wv][c2];
            rank += (o.x < my.x) || (o.x == my.x && o.y < my.y);
        }
        if (rank < KNN) idx[ia * KNN + rank] = (int)my.y;
    }
}

// ------- per-atom attention, wave-per-atom, 2 atoms/WG, barrier-free -------
#define WPA 2

__global__ __launch_bounds__(128) void k_attn(
    const float* __restrict__ xyz, const int* __restrict__ seq,
    const int* __restrict__ num_bonds, const float* __restrict__ state,
    const float* __restrict__ grads,
    const float* __restrict__ We, const float* __restrict__ be,
    const float* __restrict__ Wq, const float* __restrict__ Wk,
    const float* __restrict__ Wv0, const float* __restrict__ Wv1,
    const float* __restrict__ Wo0, const float* __restrict__ Wself,
    const float* __restrict__ b0,
    const float4* __restrict__ pact, const int* __restrict__ cnt,
    const int* __restrict__ idxbuf,
    float* __restrict__ out_xyz, float* __restrict__ out_state) {

    __shared__ float sh_kin[WPA][KNN][100];  // [node0|e|inv|pad]; reused for coef at end
    __shared__ float sh_u[WPA][800];         // rbf[384] -> qw[400] -> {v1[0:384] | wkin[400:800]}
    __shared__ float sh_dir[WPA][KNN][4];
    __shared__ float sh_l1j[WPA][KNN][9];
    __shared__ float sh_qin[WPA][68];
    __shared__ float sh_qo[WPA][64];         // q, later o0
    __shared__ float sh_la[WPA][4][KNN];     // logits, overwritten by attn
    __shared__ int   sh_j[WPA][KNN];
    __shared__ int   sh_bc[WPA][KNN];
    __shared__ float sh_xi[WPA][4];

    const int nact = *cnt;
    const int w = threadIdx.x >> 6;
    const int lane = threadIdx.x & 63;
    const int slot = blockIdx.x * WPA + w;
    if (slot >= nact) return;                // wave-uniform; kernel has NO block barriers
    const int i = __float_as_int(pact[slot].w);
    const int l15 = lane & 15;
    const int h = lane >> 4;

    float (*kin)[100] = sh_kin[w];
    float* uu         = sh_u[w];
    float (*dir)[4]   = sh_dir[w];
    float (*l1j)[9]   = sh_l1j[w];
    float* qin        = sh_qin[w];
    float* qo         = sh_qo[w];
    float (*la)[KNN]  = sh_la[w];
    int* sj           = sh_j[w];
    int* sbc          = sh_bc[w];
    float* xi         = sh_xi[w];

    // ---- stage per-atom inputs ----
    qin[lane] = state[i * D0_ + lane];
    if (lane < 3) {
        float g0 = grads[(lane * MTOT + i) * 3 + 0];
        float g1 = grads[(lane * MTOT + i) * 3 + 1];
        float g2 = grads[(lane * MTOT + i) * 3 + 2];
        qin[D0_ + lane] = sqrtf(g0 * g0 + g1 * g1 + g2 * g2 + EPS_);
        xi[lane] = xyz[i * 3 + lane];
    }
    if (lane < KNN) {
        int j = idxbuf[i * KNN + lane];
        int jj = min(max(j, 0), MTOT - 1);
        sj[lane] = jj;
        float dx = xyz[jj * 3 + 0] - xyz[i * 3 + 0];
        float dy = xyz[jj * 3 + 1] - xyz[i * 3 + 1];
        float dz = xyz[jj * 3 + 2] - xyz[i * 3 + 2];
        float dist = sqrtf(dx * dx + dy * dy + dz * dz + EPS_);
        dir[lane][0] = dx / dist;
        dir[lane][1] = dy / dist;
        dir[lane][2] = dz / dist;
        dir[lane][3] = dist;
        int ri = i / A_, ai = i - ri * A_;
        int rj = jj / A_, aj = jj - rj * A_;
        int b = 0;
        if (rj == ri) b = num_bonds[(seq[ri] * A_ + ai) * A_ + aj];
        sbc[lane] = min(max(b, 0), 4);
    }
    __builtin_amdgcn_wave_barrier();

    // ---- q projection ----
    {
        float q = 0.0f;
        for (int c = 0; c < QIN_; ++c) q += qin[c] * Wq[c * 64 + lane];
        qo[lane] = q;
    }
    // ---- rbf -> uu[0:384] ----
    for (int f = lane; f < KNN * RBF_; f += 64) {
        int k = f >> 4, r = f & 15;
        float mu = (6.0f / 15.0f) * (float)r;
        float d = dir[k][3] - mu;
        uu[k * 16 + r] = expf(-d * d * 2.0f);
    }
    // ---- neighbor node0 gather ----
    for (int k = 0; k < KNN; ++k) kin[k][lane] = state[sj[k] * D0_ + lane];
    // ---- l1 invariants + stash l1j ----
    for (int f = lane; f < KNN * 3; f += 64) {
        int k = f / 3, c = f - 3 * k;
        int jj = sj[k];
        float g0 = grads[(c * MTOT + jj) * 3 + 0];
        float g1 = grads[(c * MTOT + jj) * 3 + 1];
        float g2 = grads[(c * MTOT + jj) * 3 + 2];
        l1j[k][c * 3 + 0] = g0; l1j[k][c * 3 + 1] = g1; l1j[k][c * 3 + 2] = g2;
        kin[k][96 + c] = g0 * dir[k][0] + g1 * dir[k][1] + g2 * dir[k][2];
    }
    if (lane < KNN) kin[lane][99] = 0.0f;
    __builtin_amdgcn_wave_barrier();

    // ---- edge embedding -> kin[:, 64:96] (consumes rbf) ----
    for (int f = lane; f < KNN * EDGE_; f += 64) {
        int k = f >> 5, d = f & 31;
        float acc = be[d] + We[(RBF_ + sbc[k]) * EDGE_ + d];
        #pragma unroll
        for (int r = 0; r < RBF_; ++r) acc += uu[k * 16 + r] * We[r * EDGE_ + d];
        kin[k][64 + d] = acc;
    }
    __builtin_amdgcn_wave_barrier();

    // ---- fold q into Wk: qW[h][c] -> uu[0:400] (rbf dead) ----
    for (int t = 0; t < 7; ++t) {
        int c = t * 16 + l15;
        if (c < 99) {
            const float* wk = &Wk[c * 64 + h * 16];
            float acc = 0.0f;
            #pragma unroll
            for (int d = 0; d < 16; ++d) acc += qo[h * 16 + d] * wk[d];
            uu[h * 100 + c] = acc;
        }
    }
    __builtin_amdgcn_wave_barrier();

    // ---- logits[h][k] = kin[k] . qW[h] ----
    for (int f = lane; f < 96; f += 64) {
        int k = f >> 2, hh = f & 3;
        const float4* k4 = (const float4*)kin[k];
        const float4* q4 = (const float4*)&uu[hh * 100];
        float acc = 0.0f;
        #pragma unroll
        for (int c4 = 0; c4 < 24; ++c4) {
            float4 a = k4[c4], b = q4[c4];
            acc += a.x * b.x + a.y * b.y + a.z * b.z + a.w * b.w;
        }
        acc += kin[k][96] * uu[hh * 100 + 96] + kin[k][97] * uu[hh * 100 + 97]
             + kin[k][98] * uu[hh * 100 + 98];
        la[hh][k] = acc * 0.25f;
    }
    __builtin_amdgcn_wave_barrier();

    // ---- softmax (attn in regs; identical within head group) ----
    float attn[KNN];
    {
        float mx = -1e30f;
        #pragma unroll
        for (int k = 0; k < KNN; ++k) { attn[k] = la[h][k]; mx = fmaxf(mx, attn[k]); }
        float ss = 0.0f;
        #pragma unroll
        for (int k = 0; k < KNN; ++k) { attn[k] = expf(attn[k] - mx); ss += attn[k]; }
        float rs = 1.0f / ss;
        #pragma unroll
        for (int k = 0; k < KNN; ++k) attn[k] *= rs;
    }
    __builtin_amdgcn_wave_barrier();
    la[h][l15] = attn[l15];                  // overwrite logits with attn
    if (l15 < 8) la[h][16 + l15] = attn[16 + l15];

    // ---- wkin[h][c] = sum_k attn[k]*kin[k][c] -> uu[400:800] ----
    for (int t = 0; t < 7; ++t) {
        int c = t * 16 + l15;
        if (c < 99) {
            float acc = 0.0f;
            #pragma unroll
            for (int k = 0; k < KNN; ++k) acc += attn[k] * kin[k][c];
            uu[400 + h * 100 + c] = acc;
        }
    }
    // ---- v1[k][u] = kin[k] . Wv1[:,u] -> uu[0:384] (qw dead) ----
    for (int t = 0; t < 6; ++t) {
        int k = (t * 64 + lane) >> 4;
        const float4* k4 = (const float4*)kin[k];
        const float* wv = &Wv1[l15];
        float acc = 0.0f;
        #pragma unroll
        for (int c4 = 0; c4 < 24; ++c4) {
            float4 a = k4[c4];
            acc += a.x * wv[(c4 * 4 + 0) * 16] + a.y * wv[(c4 * 4 + 1) * 16]
                 + a.z * wv[(c4 * 4 + 2) * 16] + a.w * wv[(c4 * 4 + 3) * 16];
        }
        acc += kin[k][96] * wv[96 * 16] + kin[k][97] * wv[97 * 16]
             + kin[k][98] * wv[98 * 16];
        uu[k * 16 + l15] = acc;
    }
    __builtin_amdgcn_wave_barrier();

    // ---- o0[lane] = wkin[h] . Wv0[:, lane] -> qo (q dead) ----
    {
        float o0 = 0.0f;
        for (int c = 0; c < 99; ++c) o0 += uu[400 + h * 100 + c] * Wv0[c * 64 + lane];
        qo[lane] = o0;
    }
    __builtin_amdgcn_wave_barrier();

    // ---- out0 = o0 @ Wo0 + node0 @ Wself + b0 ----
    {
        float acc = b0[lane];
        for (int t = 0; t < 64; ++t) acc += qo[t] * Wo0[t * 64 + lane];
        for (int t = 0; t < 64; ++t) acc += qin[t] * Wself[t * 64 + lane];
        out_state[i * D0_ + lane] = acc;
    }
    // ---- coef[k][c] = sum_h attn_sh[h][k] * v1[k][h*4+c] -> overlay on kin ----
    float* coef = &kin[0][0];                // kin dead; 96 floats
    for (int f = lane; f < KNN * 4; f += 64) {
        int k = f >> 2, c = f & 3;
        float a2 = 0.0f;
        #pragma unroll
        for (int hh = 0; hh < 4; ++hh) a2 += la[hh][k] * uu[k * 16 + hh * 4 + c];
        coef[k * 4 + c] = a2;
    }
    __builtin_amdgcn_wave_barrier();

    // ---- vector message -> xyz shift ----
    if (lane < 3) {
        float o1 = 0.0f;
        #pragma unroll
        for (int k = 0; k < KNN; ++k) {
            float t = coef[k * 4 + 0] * dir[k][lane];
            t += coef[k * 4 + 1] * l1j[k][0 + lane];
            t += coef[k * 4 + 2] * l1j[k][3 + lane];
            t += coef[k * 4 + 3] * l1j[k][6 + lane];
            o1 += t;
        }
        out_xyz[i * 3 + lane] = xi[lane] + o1 / 100.0f;
    }
}

extern "C" void kernel_launch(void* const* d_in, const int* in_sizes, int n_in,
                              void* d_out, int out_size, void* d_ws, size_t ws_size,
                              hipStream_t stream) {
    const int*   seq    = (const int*)d_in[0];
    const float* xyz    = (const float*)d_in[1];
    const int*   aamask = (const int*)d_in[2];
    const int*   nbonds = (const int*)d_in[3];
    const float* state  = (const float*)d_in[4];
    const float* grads  = (const float*)d_in[5];
    const float* We    = (const float*)d_in[7];
    const float* be    = (const float*)d_in[8];
    const float* Wq    = (const float*)d_in[9];
    const float* Wk    = (const float*)d_in[10];
    const float* Wv0   = (const float*)d_in[11];
    const float* Wv1   = (const float*)d_in[12];
    const float* Wo0   = (const float*)d_in[13];
    const float* Wself = (const float*)d_in[14];
    const float* b0    = (const float*)d_in[15];

    float* out_xyz   = (float*)d_out;
    float* out_state = out_xyz + MTOT * 3;

    char* ws = (char*)d_ws;
    int*    cnt  = (int*)ws;                              // 16 B
    float4* pact = (float4*)(ws + 16);                    // (MTOT+128)*16 = 149504 B
    int*    idx  = (int*)(ws + 16 + 149504);              // 884736 B

    hipMemsetAsync(cnt, 0, 16, stream);
    k_prep<<<(MTOT * D0_ / 4 + 255) / 256, 256, 0, stream>>>(
        seq, xyz, aamask, (const float4*)state, (float4*)out_state,
        pact, out_xyz, cnt);
    k_nbr<<<(MTOT + WPB - 1) / WPB, 512, 0, stream>>>(pact, cnt, idx);
    k_attn<<<(MTOT + WPA - 1) / WPA, 64 * WPA, 0, stream>>>(
        xyz, seq, nbonds, state, grads, We, be, Wq, Wk, Wv0, Wv1, Wo0, Wself, b0,
        pact, cnt, idx, out_xyz, out_state);
}

// Round 6
// 225.425 us; speedup vs baseline: 1.6027x; 1.6027x over previous
//
#include <hip/hip_runtime.h>
#include <math.h>

#define MTOT 9216
#define A_ 36
#define D0_ 64
#define EDGE_ 32
#define RBF_ 16
#define KNN 24
#define QIN_ 67    // D0 + KC
#define EPS_ 1e-5f

// ---- prep: state passthrough copy + pact build + xyz passthrough (fused) ----
__global__ void k_prep(const int* __restrict__ seq, const float* __restrict__ xyz,
                       const int* __restrict__ aamask,
                       const float4* __restrict__ state4, float4* __restrict__ out_state4,
                       float4* __restrict__ pact, float* __restrict__ out_xyz,
                       int* __restrict__ cnt) {
    int t = blockIdx.x * blockDim.x + threadIdx.x;
    if (t < MTOT * D0_ / 4) out_state4[t] = state4[t];
    if (t < MTOT) {
        int r = t / A_;
        int a = t - r * A_;
        int mk = (aamask[seq[r] * A_ + a] != 0);
        float x0 = xyz[t * 3 + 0], x1 = xyz[t * 3 + 1], x2 = xyz[t * 3 + 2];
        out_xyz[t * 3 + 0] = x0;
        out_xyz[t * 3 + 1] = x1;
        out_xyz[t * 3 + 2] = x2;
        if (mk) {
            int p = atomicAdd(cnt, 1);   // compiler wave-aggregates
            pact[p] = make_float4(x0, x1, x2, __int_as_float(t));
        }
    }
}

// ------- exact top-24, wave-per-atom, ballot histogram (R3 base, 16 ballots) ---
#define CAPN 256
#define WPB 4    // waves per block (R3-validated dispatch shape)

__global__ __launch_bounds__(256) void k_nbr(const float4* __restrict__ pact,
                                             const int* __restrict__ cnt,
                                             int* __restrict__ idx) {
    __shared__ uint2 s_cand[WPB][CAPN];   // per-wave slice, 8 KB total

    const int nact = *cnt;
    const int lane = threadIdx.x & 63;
    const int wv = threadIdx.x >> 6;
    const int slot = blockIdx.x * WPB + wv;
    if (slot >= nact) return;            // wave-uniform exit; no block barriers

    const float4 pq = pact[slot];
    const int ia = __float_as_int(pq.w);
    const unsigned long long lmask = (1ULL << lane) - 1ULL;

    // ---- pass A: cumulative histogram at 16 coarse thresholds (bins 2b+1) ----
    unsigned cum[16];
    #pragma unroll
    for (int b = 0; b < 16; ++b) cum[b] = 0u;

    for (int base = 0; base < nact; base += 64) {
        int c = base + lane;                      // pact padded: OOB-safe read
        float4 p = pact[c];
        int j = __float_as_int(p.w);
        float dx = p.x - pq.x, dy = p.y - pq.y, dz = p.z - pq.z;
        float d2 = dx * dx + dy * dy + dz * dz;
        int bb = min(max((int)(__float_as_uint(d2) >> 22) - 240, 0), 31);
        unsigned bin = (c < nact && j != ia) ? (unsigned)bb : 1000u;
        #pragma unroll
        for (int b = 0; b < 16; ++b)
            cum[b] += (unsigned)__popcll(__ballot(bin <= (unsigned)(2 * b + 1)));
    }

    // ---- threshold bin of the 24th smallest (uniform across lanes) ----
    int bsel = 15;
    #pragma unroll
    for (int b = 15; b >= 0; --b) if (cum[b] >= KNN) bsel = b;
    const unsigned limit = (unsigned)(242 + 2 * bsel) << 22;

    // ---- pass B: ballot-compacted candidate collection (superset of top-24) ----
    int nsel = 0;
    for (int base = 0; base < nact; base += 64) {
        int c = base + lane;
        float4 p = pact[c];
        int j = __float_as_int(p.w);
        float dx = p.x - pq.x, dy = p.y - pq.y, dz = p.z - pq.z;
        float d2 = dx * dx + dy * dy + dz * dz;
        unsigned bits = __float_as_uint(d2);
        bool sel = (c < nact) && (j != ia) && (bits < limit);
        unsigned long long m = __ballot(sel);
        int pos = nsel + (int)__popcll(m & lmask);
        if (sel && pos < CAPN) s_cand[wv][pos] = make_uint2(bits, (unsigned)j);
        nsel += (int)__popcll(m);
    }
    __builtin_amdgcn_wave_barrier();

    // ---- exact rank select ((d2, j) lex == lax.top_k tie-break) ----
    int n = min(nsel, CAPN);
    for (int c = lane; c < n; c += 64) {
        uint2 my = s_cand[wv][c];
        int rank = 0;
        for (int c2 = 0; c2 < n; ++c2) {
            uint2 o = s_cand[wv][c2];
            rank += (o.x < my.x) || (o.x == my.x && o.y < my.y);
        }
        if (rank < KNN) idx[ia * KNN + rank] = (int)my.y;
    }
}

// ---------------- per-atom attention, rank-reduced (R3 kernel, verbatim) -------
__global__ __launch_bounds__(64, 2) void k_attn(
    const float* __restrict__ xyz, const int* __restrict__ seq,
    const int* __restrict__ num_bonds, const float* __restrict__ state,
    const float* __restrict__ grads,
    const float* __restrict__ We, const float* __restrict__ be,
    const float* __restrict__ Wq, const float* __restrict__ Wk,
    const float* __restrict__ Wv0, const float* __restrict__ Wv1,
    const float* __restrict__ Wo0, const float* __restrict__ Wself,
    const float* __restrict__ b0,
    const float4* __restrict__ pact, const int* __restrict__ cnt,
    const int* __restrict__ idxbuf,
    float* __restrict__ out_xyz, float* __restrict__ out_state) {
    const int nact = *cnt;
    if ((int)blockIdx.x >= nact) return;
    const int i = __float_as_int(pact[blockIdx.x].w);
    const int lane = threadIdx.x;
    const int l15 = lane & 15;
    const int h = lane >> 4;

    __shared__ float s_kin[KNN][100];   // [node0(64) | e(32) | inv(3) | pad]
    __shared__ float s_qw[4][100];      // Wk folded with q, per head
    __shared__ float s_wkin[4][100];    // attn-weighted kin, per head
    __shared__ float s_dir[KNN][4];
    __shared__ float s_rbf[KNN][RBF_];
    __shared__ float s_l1j[KNN][3][3];
    __shared__ float s_qin[68];
    __shared__ float s_q[64];
    __shared__ float s_logit[4][KNN];
    __shared__ float s_attn[4][KNN];
    __shared__ float s_o0[64];
    __shared__ float s_v1[KNN][16];
    __shared__ float s_coef[KNN][4];
    __shared__ int   s_j[KNN];
    __shared__ int   s_ok[KNN];
    __shared__ int   s_bc[KNN];
    __shared__ float s_xi[3];

    // ---- stage per-atom inputs ----
    s_qin[lane] = state[i * D0_ + lane];
    if (lane < 3) {
        float g0 = grads[(lane * MTOT + i) * 3 + 0];
        float g1 = grads[(lane * MTOT + i) * 3 + 1];
        float g2 = grads[(lane * MTOT + i) * 3 + 2];
        s_qin[D0_ + lane] = sqrtf(g0 * g0 + g1 * g1 + g2 * g2 + EPS_);
        s_xi[lane] = xyz[i * 3 + lane];
    }
    if (lane < KNN) {
        int j = idxbuf[i * KNN + lane];
        int ok = (j >= 0 && j < MTOT);
        int jj = ok ? j : 0;
        s_j[lane] = jj;
        s_ok[lane] = ok;
        float dx = xyz[jj * 3 + 0] - xyz[i * 3 + 0];
        float dy = xyz[jj * 3 + 1] - xyz[i * 3 + 1];
        float dz = xyz[jj * 3 + 2] - xyz[i * 3 + 2];
        float dist = sqrtf(dx * dx + dy * dy + dz * dz + EPS_);
        s_dir[lane][0] = dx / dist;
        s_dir[lane][1] = dy / dist;
        s_dir[lane][2] = dz / dist;
        s_dir[lane][3] = dist;
        int ri = i / A_, ai = i - ri * A_;
        int rj = jj / A_, aj = jj - rj * A_;
        int b = 0;
        if (rj == ri) b = num_bonds[(seq[ri] * A_ + ai) * A_ + aj];
        s_bc[lane] = min(max(b, 0), 4);
    }
    __syncthreads();

    // ---- q projection ----
    {
        float q = 0.0f;
        for (int c = 0; c < QIN_; ++c) q += s_qin[c] * Wq[c * 64 + lane];
        s_q[lane] = q;
    }
    // ---- rbf ----
    for (int f = lane; f < KNN * RBF_; f += 64) {
        int k = f >> 4, r = f & 15;
        float mu = (6.0f / 15.0f) * (float)r;
        float d = s_dir[k][3] - mu;
        s_rbf[k][r] = expf(-d * d * 2.0f);
    }
    // ---- neighbor node0 gather ----
    for (int k = 0; k < KNN; ++k) s_kin[k][lane] = state[s_j[k] * D0_ + lane];
    // ---- l1 invariants + stash l1j ----
    for (int f = lane; f < KNN * 3; f += 64) {
        int k = f / 3, c = f - 3 * k;
        int jj = s_j[k];
        float g0 = grads[(c * MTOT + jj) * 3 + 0];
        float g1 = grads[(c * MTOT + jj) * 3 + 1];
        float g2 = grads[(c * MTOT + jj) * 3 + 2];
        s_l1j[k][c][0] = g0; s_l1j[k][c][1] = g1; s_l1j[k][c][2] = g2;
        s_kin[k][96 + c] = g0 * s_dir[k][0] + g1 * s_dir[k][1] + g2 * s_dir[k][2];
    }
    if (lane < KNN) s_kin[lane][99] = 0.0f;
    __syncthreads();

    // ---- edge embedding -> kin[:, 64:96] ----
    for (int f = lane; f < KNN * EDGE_; f += 64) {
        int k = f >> 5, d = f & 31;
        float acc = be[d] + We[(RBF_ + s_bc[k]) * EDGE_ + d];
        #pragma unroll
        for (int r = 0; r < RBF_; ++r) acc += s_rbf[k][r] * We[r * EDGE_ + d];
        s_kin[k][64 + d] = acc;
    }
    // ---- fold q into Wk: qW[h][c] = sum_d q[h,d] * Wk[c, h*16+d] ----
    for (int t = 0; t < 7; ++t) {
        int c = t * 16 + l15;
        if (c < 99) {
            const float* wk = &Wk[c * 64 + h * 16];
            float acc = 0.0f;
            #pragma unroll
            for (int d = 0; d < 16; ++d) acc += s_q[h * 16 + d] * wk[d];
            s_qw[h][c] = acc;
        }
    }
    __syncthreads();

    // ---- logits[h][k] = kin[k] . qW[h] ----
    for (int f = lane; f < 96; f += 64) {
        int k = f >> 2, hh = f & 3;
        const float4* k4 = (const float4*)s_kin[k];
        const float4* q4 = (const float4*)s_qw[hh];
        float acc = 0.0f;
        #pragma unroll
        for (int c4 = 0; c4 < 24; ++c4) {
            float4 a = k4[c4], b = q4[c4];
            acc += a.x * b.x + a.y * b.y + a.z * b.z + a.w * b.w;
        }
        acc += s_kin[k][96] * s_qw[hh][96] + s_kin[k][97] * s_qw[hh][97]
             + s_kin[k][98] * s_qw[hh][98];
        s_logit[hh][k] = s_ok[k] ? acc * 0.25f : -1e9f;
    }
    __syncthreads();

    // ---- softmax ----
    float attn[KNN];
    {
        float mx = -1e30f;
        #pragma unroll
        for (int k = 0; k < KNN; ++k) { attn[k] = s_logit[h][k]; mx = fmaxf(mx, attn[k]); }
        float ss = 0.0f;
        #pragma unroll
        for (int k = 0; k < KNN; ++k) { attn[k] = expf(attn[k] - mx); ss += attn[k]; }
        float rs = 1.0f / ss;
        #pragma unroll
        for (int k = 0; k < KNN; ++k) attn[k] *= rs;
    }
    s_attn[h][l15] = attn[l15];
    if (l15 < 8) s_attn[h][16 + l15] = attn[16 + l15];

    // ---- wkin[h][c] = sum_k attn[k] * kin[k][c] ----
    for (int t = 0; t < 7; ++t) {
        int c = t * 16 + l15;
        if (c < 99) {
            float acc = 0.0f;
            #pragma unroll
            for (int k = 0; k < KNN; ++k) acc += attn[k] * s_kin[k][c];
            s_wkin[h][c] = acc;
        }
    }
    // ---- v1[k][u] = kin[k] . Wv1[:,u] ----
    for (int t = 0; t < 6; ++t) {
        int k = (t * 64 + lane) >> 4;
        const float4* k4 = (const float4*)s_kin[k];
        const float* wv = &Wv1[l15];
        float acc = 0.0f;
        #pragma unroll
        for (int c4 = 0; c4 < 24; ++c4) {
            float4 a = k4[c4];
            acc += a.x * wv[(c4 * 4 + 0) * 16] + a.y * wv[(c4 * 4 + 1) * 16]
                 + a.z * wv[(c4 * 4 + 2) * 16] + a.w * wv[(c4 * 4 + 3) * 16];
        }
        acc += s_kin[k][96] * wv[96 * 16] + s_kin[k][97] * wv[97 * 16]
             + s_kin[k][98] * wv[98 * 16];
        s_v1[k][l15] = acc;
    }
    __syncthreads();

    // ---- o0[lane] = sum_c wkin[h][c] * Wv0[c, lane] ----
    {
        float o0 = 0.0f;
        for (int c = 0; c < 99; ++c) o0 += s_wkin[h][c] * Wv0[c * 64 + lane];
        s_o0[lane] = o0;
    }
    __syncthreads();

    // ---- out0 = o0 @ Wo0 + node0 @ Wself + b0 ----
    {
        float acc = b0[lane];
        for (int t = 0; t < 64; ++t) acc += s_o0[t] * Wo0[t * 64 + lane];
        for (int t = 0; t < 64; ++t) acc += s_qin[t] * Wself[t * 64 + lane];
        out_state[i * D0_ + lane] = acc;
    }
    // ---- coef[k][c] = sum_h attn[h][k] * v1[k][h*4+c] ----
    for (int f = lane; f < KNN * 4; f += 64) {
        int k = f >> 2, c = f & 3;
        float a2 = 0.0f;
        #pragma unroll
        for (int hh = 0; hh < 4; ++hh) a2 += s_attn[hh][k] * s_v1[k][hh * 4 + c];
        s_coef[k][c] = a2;
    }
    __syncthreads();

    // ---- vector message -> xyz shift ----
    if (lane < 3) {
        float o1 = 0.0f;
        #pragma unroll
        for (int k = 0; k < KNN; ++k) {
            float t = s_coef[k][0] * s_dir[k][lane];
            t += s_coef[k][1] * s_l1j[k][0][lane];
            t += s_coef[k][2] * s_l1j[k][1][lane];
            t += s_coef[k][3] * s_l1j[k][2][lane];
            o1 += t;
        }
        out_xyz[i * 3 + lane] = s_xi[lane] + o1 / 100.0f;
    }
}

extern "C" void kernel_launch(void* const* d_in, const int* in_sizes, int n_in,
                              void* d_out, int out_size, void* d_ws, size_t ws_size,
                              hipStream_t stream) {
    const int*   seq    = (const int*)d_in[0];
    const float* xyz    = (const float*)d_in[1];
    const int*   aamask = (const int*)d_in[2];
    const int*   nbonds = (const int*)d_in[3];
    const float* state  = (const float*)d_in[4];
    const float* grads  = (const float*)d_in[5];
    const float* We    = (const float*)d_in[7];
    const float* be    = (const float*)d_in[8];
    const float* Wq    = (const float*)d_in[9];
    const float* Wk    = (const float*)d_in[10];
    const float* Wv0   = (const float*)d_in[11];
    const float* Wv1   = (const float*)d_in[12];
    const float* Wo0   = (const float*)d_in[13];
    const float* Wself = (const float*)d_in[14];
    const float* b0    = (const float*)d_in[15];

    float* out_xyz   = (float*)d_out;
    float* out_state = out_xyz + MTOT * 3;

    char* ws = (char*)d_ws;
    int*    cnt  = (int*)ws;                              // 16 B
    float4* pact = (float4*)(ws + 16);                    // (MTOT+128)*16 = 149504 B
    int*    idx  = (int*)(ws + 16 + 149504);              // 884736 B

    hipMemsetAsync(cnt, 0, 16, stream);
    k_prep<<<(MTOT * D0_ / 4 + 255) / 256, 256, 0, stream>>>(
        seq, xyz, aamask, (const float4*)state, (float4*)out_state,
        pact, out_xyz, cnt);
    k_nbr<<<(MTOT + WPB - 1) / WPB, 256, 0, stream>>>(pact, cnt, idx);
    k_attn<<<MTOT, 64, 0, stream>>>(xyz, seq, nbonds, state, grads, We, be, Wq, Wk,
                                    Wv0, Wv1, Wo0, Wself, b0, pact, cnt, idx,
                                    out_xyz, out_state);
}

// Round 7
// 216.870 us; speedup vs baseline: 1.6659x; 1.0394x over previous
//
#include <hip/hip_runtime.h>
#include <math.h>

#define MTOT 9216
#define A_ 36
#define D0_ 64
#define EDGE_ 32
#define RBF_ 16
#define KNN 24
#define QIN_ 67    // D0 + KC
#define EPS_ 1e-5f

// ---- prep: state passthrough copy + pact build + xyz passthrough (fused) ----
__global__ void k_prep(const int* __restrict__ seq, const float* __restrict__ xyz,
                       const int* __restrict__ aamask,
                       const float4* __restrict__ state4, float4* __restrict__ out_state4,
                       float4* __restrict__ pact, float* __restrict__ out_xyz,
                       int* __restrict__ cnt) {
    int t = blockIdx.x * blockDim.x + threadIdx.x;
    if (t < MTOT * D0_ / 4) out_state4[t] = state4[t];
    if (t < MTOT) {
        int r = t / A_;
        int a = t - r * A_;
        int mk = (aamask[seq[r] * A_ + a] != 0);
        float x0 = xyz[t * 3 + 0], x1 = xyz[t * 3 + 1], x2 = xyz[t * 3 + 2];
        out_xyz[t * 3 + 0] = x0;
        out_xyz[t * 3 + 1] = x1;
        out_xyz[t * 3 + 2] = x2;
        if (mk) {
            int p = atomicAdd(cnt, 1);   // compiler wave-aggregates
            pact[p] = make_float4(x0, x1, x2, __int_as_float(t));
        }
    }
}

// ------- exact top-24, wave-per-atom, ballot histogram, 4-deep load pipeline ---
#define CAPN 256
#define WPB 8
#define UNR 4

__global__ __launch_bounds__(512) void k_nbr(const float4* __restrict__ pact,
                                             const int* __restrict__ cnt,
                                             int* __restrict__ idx) {
    __shared__ uint2 s_cand[WPB][CAPN];   // per-wave slice, 16 KB total

    const int nact = *cnt;
    const int lane = threadIdx.x & 63;
    const int wv = threadIdx.x >> 6;
    const int slot = blockIdx.x * WPB + wv;
    if (slot >= nact) return;            // wave-uniform exit; no block barriers

    const float4 pq = pact[slot];
    const int ia = __float_as_int(pq.w);
    const unsigned long long lmask = (1ULL << lane) - 1ULL;

    // ---- pass A: cumulative histogram, 16 raw-bits thresholds, 4-deep MLP ----
    unsigned cum[16];
    #pragma unroll
    for (int b = 0; b < 16; ++b) cum[b] = 0u;

    for (int base = 0; base < nact; base += 64 * UNR) {
        float4 p[UNR];
        #pragma unroll
        for (int u = 0; u < UNR; ++u) p[u] = pact[base + u * 64 + lane];  // padded: OOB-safe
        unsigned bt[UNR];
        #pragma unroll
        for (int u = 0; u < UNR; ++u) {
            int c = base + u * 64 + lane;
            int j = __float_as_int(p[u].w);
            float dx = p[u].x - pq.x, dy = p[u].y - pq.y, dz = p[u].z - pq.z;
            float d2 = dx * dx + dy * dy + dz * dz;
            bt[u] = (c < nact && j != ia) ? __float_as_uint(d2) : 0xFFFFFFFFu;
        }
        #pragma unroll
        for (int b = 0; b < 16; ++b) {
            const unsigned L = (unsigned)(242 + 2 * b) << 22;   // == bin <= 2b+1
            unsigned s = 0;
            #pragma unroll
            for (int u = 0; u < UNR; ++u)
                s += (unsigned)__popcll(__ballot(bt[u] < L));
            cum[b] += s;
        }
    }

    // ---- threshold of the 24th smallest (uniform across lanes) ----
    int bsel = 15;
    #pragma unroll
    for (int b = 15; b >= 0; --b) if (cum[b] >= KNN) bsel = b;
    const unsigned limit = (unsigned)(242 + 2 * bsel) << 22;

    // ---- pass B: ballot-compacted candidate collection (superset of top-24) ----
    int nsel = 0;
    for (int base = 0; base < nact; base += 64 * UNR) {
        float4 p[UNR];
        #pragma unroll
        for (int u = 0; u < UNR; ++u) p[u] = pact[base + u * 64 + lane];
        #pragma unroll
        for (int u = 0; u < UNR; ++u) {
            int c = base + u * 64 + lane;
            int j = __float_as_int(p[u].w);
            float dx = p[u].x - pq.x, dy = p[u].y - pq.y, dz = p[u].z - pq.z;
            float d2 = dx * dx + dy * dy + dz * dz;
            unsigned bits = (c < nact && j != ia) ? __float_as_uint(d2) : 0xFFFFFFFFu;
            bool sel = bits < limit;
            unsigned long long m = __ballot(sel);
            int pos = nsel + (int)__popcll(m & lmask);
            if (sel && pos < CAPN) s_cand[wv][pos] = make_uint2(bits, (unsigned)j);
            nsel += (int)__popcll(m);
        }
    }
    __builtin_amdgcn_wave_barrier();

    // ---- exact rank select ((d2, j) lex == lax.top_k tie-break) ----
    int n = min(nsel, CAPN);
    for (int c = lane; c < n; c += 64) {
        uint2 my = s_cand[wv][c];
        int rank = 0;
        for (int c2 = 0; c2 < n; ++c2) {
            uint2 o = s_cand[wv][c2];
            rank += (o.x < my.x) || (o.x == my.x && o.y < my.y);
        }
        if (rank < KNN) idx[ia * KNN + rank] = (int)my.y;
    }
}

// ---------------- per-atom attention, rank-reduced (R3 kernel, verbatim) -------
__global__ __launch_bounds__(64, 2) void k_attn(
    const float* __restrict__ xyz, const int* __restrict__ seq,
    const int* __restrict__ num_bonds, const float* __restrict__ state,
    const float* __restrict__ grads,
    const float* __restrict__ We, const float* __restrict__ be,
    const float* __restrict__ Wq, const float* __restrict__ Wk,
    const float* __restrict__ Wv0, const float* __restrict__ Wv1,
    const float* __restrict__ Wo0, const float* __restrict__ Wself,
    const float* __restrict__ b0,
    const float4* __restrict__ pact, const int* __restrict__ cnt,
    const int* __restrict__ idxbuf,
    float* __restrict__ out_xyz, float* __restrict__ out_state) {
    const int nact = *cnt;
    if ((int)blockIdx.x >= nact) return;
    const int i = __float_as_int(pact[blockIdx.x].w);
    const int lane = threadIdx.x;
    const int l15 = lane & 15;
    const int h = lane >> 4;

    __shared__ float s_kin[KNN][100];   // [node0(64) | e(32) | inv(3) | pad]
    __shared__ float s_qw[4][100];      // Wk folded with q, per head
    __shared__ float s_wkin[4][100];    // attn-weighted kin, per head
    __shared__ float s_dir[KNN][4];
    __shared__ float s_rbf[KNN][RBF_];
    __shared__ float s_l1j[KNN][3][3];
    __shared__ float s_qin[68];
    __shared__ float s_q[64];
    __shared__ float s_logit[4][KNN];
    __shared__ float s_attn[4][KNN];
    __shared__ float s_o0[64];
    __shared__ float s_v1[KNN][16];
    __shared__ float s_coef[KNN][4];
    __shared__ int   s_j[KNN];
    __shared__ int   s_ok[KNN];
    __shared__ int   s_bc[KNN];
    __shared__ float s_xi[3];

    // ---- stage per-atom inputs ----
    s_qin[lane] = state[i * D0_ + lane];
    if (lane < 3) {
        float g0 = grads[(lane * MTOT + i) * 3 + 0];
        float g1 = grads[(lane * MTOT + i) * 3 + 1];
        float g2 = grads[(lane * MTOT + i) * 3 + 2];
        s_qin[D0_ + lane] = sqrtf(g0 * g0 + g1 * g1 + g2 * g2 + EPS_);
        s_xi[lane] = xyz[i * 3 + lane];
    }
    if (lane < KNN) {
        int j = idxbuf[i * KNN + lane];
        int ok = (j >= 0 && j < MTOT);
        int jj = ok ? j : 0;
        s_j[lane] = jj;
        s_ok[lane] = ok;
        float dx = xyz[jj * 3 + 0] - xyz[i * 3 + 0];
        float dy = xyz[jj * 3 + 1] - xyz[i * 3 + 1];
        float dz = xyz[jj * 3 + 2] - xyz[i * 3 + 2];
        float dist = sqrtf(dx * dx + dy * dy + dz * dz + EPS_);
        s_dir[lane][0] = dx / dist;
        s_dir[lane][1] = dy / dist;
        s_dir[lane][2] = dz / dist;
        s_dir[lane][3] = dist;
        int ri = i / A_, ai = i - ri * A_;
        int rj = jj / A_, aj = jj - rj * A_;
        int b = 0;
        if (rj == ri) b = num_bonds[(seq[ri] * A_ + ai) * A_ + aj];
        s_bc[lane] = min(max(b, 0), 4);
    }
    __syncthreads();

    // ---- q projection ----
    {
        float q = 0.0f;
        for (int c = 0; c < QIN_; ++c) q += s_qin[c] * Wq[c * 64 + lane];
        s_q[lane] = q;
    }
    // ---- rbf ----
    for (int f = lane; f < KNN * RBF_; f += 64) {
        int k = f >> 4, r = f & 15;
        float mu = (6.0f / 15.0f) * (float)r;
        float d = s_dir[k][3] - mu;
        s_rbf[k][r] = expf(-d * d * 2.0f);
    }
    // ---- neighbor node0 gather ----
    for (int k = 0; k < KNN; ++k) s_kin[k][lane] = state[s_j[k] * D0_ + lane];
    // ---- l1 invariants + stash l1j ----
    for (int f = lane; f < KNN * 3; f += 64) {
        int k = f / 3, c = f - 3 * k;
        int jj = s_j[k];
        float g0 = grads[(c * MTOT + jj) * 3 + 0];
        float g1 = grads[(c * MTOT + jj) * 3 + 1];
        float g2 = grads[(c * MTOT + jj) * 3 + 2];
        s_l1j[k][c][0] = g0; s_l1j[k][c][1] = g1; s_l1j[k][c][2] = g2;
        s_kin[k][96 + c] = g0 * s_dir[k][0] + g1 * s_dir[k][1] + g2 * s_dir[k][2];
    }
    if (lane < KNN) s_kin[lane][99] = 0.0f;
    __syncthreads();

    // ---- edge embedding -> kin[:, 64:96] ----
    for (int f = lane; f < KNN * EDGE_; f += 64) {
        int k = f >> 5, d = f & 31;
        float acc = be[d] + We[(RBF_ + s_bc[k]) * EDGE_ + d];
        #pragma unroll
        for (int r = 0; r < RBF_; ++r) acc += s_rbf[k][r] * We[r * EDGE_ + d];
        s_kin[k][64 + d] = acc;
    }
    // ---- fold q into Wk: qW[h][c] = sum_d q[h,d] * Wk[c, h*16+d] ----
    for (int t = 0; t < 7; ++t) {
        int c = t * 16 + l15;
        if (c < 99) {
            const float* wk = &Wk[c * 64 + h * 16];
            float acc = 0.0f;
            #pragma unroll
            for (int d = 0; d < 16; ++d) acc += s_q[h * 16 + d] * wk[d];
            s_qw[h][c] = acc;
        }
    }
    __syncthreads();

    // ---- logits[h][k] = kin[k] . qW[h] ----
    for (int f = lane; f < 96; f += 64) {
        int k = f >> 2, hh = f & 3;
        const float4* k4 = (const float4*)s_kin[k];
        const float4* q4 = (const float4*)s_qw[hh];
        float acc = 0.0f;
        #pragma unroll
        for (int c4 = 0; c4 < 24; ++c4) {
            float4 a = k4[c4], b = q4[c4];
            acc += a.x * b.x + a.y * b.y + a.z * b.z + a.w * b.w;
        }
        acc += s_kin[k][96] * s_qw[hh][96] + s_kin[k][97] * s_qw[hh][97]
             + s_kin[k][98] * s_qw[hh][98];
        s_logit[hh][k] = s_ok[k] ? acc * 0.25f : -1e9f;
    }
    __syncthreads();

    // ---- softmax ----
    float attn[KNN];
    {
        float mx = -1e30f;
        #pragma unroll
        for (int k = 0; k < KNN; ++k) { attn[k] = s_logit[h][k]; mx = fmaxf(mx, attn[k]); }
        float ss = 0.0f;
        #pragma unroll
        for (int k = 0; k < KNN; ++k) { attn[k] = expf(attn[k] - mx); ss += attn[k]; }
        float rs = 1.0f / ss;
        #pragma unroll
        for (int k = 0; k < KNN; ++k) attn[k] *= rs;
    }
    s_attn[h][l15] = attn[l15];
    if (l15 < 8) s_attn[h][16 + l15] = attn[16 + l15];

    // ---- wkin[h][c] = sum_k attn[k] * kin[k][c] ----
    for (int t = 0; t < 7; ++t) {
        int c = t * 16 + l15;
        if (c < 99) {
            float acc = 0.0f;
            #pragma unroll
            for (int k = 0; k < KNN; ++k) acc += attn[k] * s_kin[k][c];
            s_wkin[h][c] = acc;
        }
    }
    // ---- v1[k][u] = kin[k] . Wv1[:,u] ----
    for (int t = 0; t < 6; ++t) {
        int k = (t * 64 + lane) >> 4;
        const float4* k4 = (const float4*)s_kin[k];
        const float* wv = &Wv1[l15];
        float acc = 0.0f;
        #pragma unroll
        for (int c4 = 0; c4 < 24; ++c4) {
            float4 a = k4[c4];
            acc += a.x * wv[(c4 * 4 + 0) * 16] + a.y * wv[(c4 * 4 + 1) * 16]
                 + a.z * wv[(c4 * 4 + 2) * 16] + a.w * wv[(c4 * 4 + 3) * 16];
        }
        acc += s_kin[k][96] * wv[96 * 16] + s_kin[k][97] * wv[97 * 16]
             + s_kin[k][98] * wv[98 * 16];
        s_v1[k][l15] = acc;
    }
    __syncthreads();

    // ---- o0[lane] = sum_c wkin[h][c] * Wv0[c, lane] ----
    {
        float o0 = 0.0f;
        for (int c = 0; c < 99; ++c) o0 += s_wkin[h][c] * Wv0[c * 64 + lane];
        s_o0[lane] = o0;
    }
    __syncthreads();

    // ---- out0 = o0 @ Wo0 + node0 @ Wself + b0 ----
    {
        float acc = b0[lane];
        for (int t = 0; t < 64; ++t) acc += s_o0[t] * Wo0[t * 64 + lane];
        for (int t = 0; t < 64; ++t) acc += s_qin[t] * Wself[t * 64 + lane];
        out_state[i * D0_ + lane] = acc;
    }
    // ---- coef[k][c] = sum_h attn[h][k] * v1[k][h*4+c] ----
    for (int f = lane; f < KNN * 4; f += 64) {
        int k = f >> 2, c = f & 3;
        float a2 = 0.0f;
        #pragma unroll
        for (int hh = 0; hh < 4; ++hh) a2 += s_attn[hh][k] * s_v1[k][hh * 4 + c];
        s_coef[k][c] = a2;
    }
    __syncthreads();

    // ---- vector message -> xyz shift ----
    if (lane < 3) {
        float o1 = 0.0f;
        #pragma unroll
        for (int k = 0; k < KNN; ++k) {
            float t = s_coef[k][0] * s_dir[k][lane];
            t += s_coef[k][1] * s_l1j[k][0][lane];
            t += s_coef[k][2] * s_l1j[k][1][lane];
            t += s_coef[k][3] * s_l1j[k][2][lane];
            o1 += t;
        }
        out_xyz[i * 3 + lane] = s_xi[lane] + o1 / 100.0f;
    }
}

extern "C" void kernel_launch(void* const* d_in, const int* in_sizes, int n_in,
                              void* d_out, int out_size, void* d_ws, size_t ws_size,
                              hipStream_t stream) {
    const int*   seq    = (const int*)d_in[0];
    const float* xyz    = (const float*)d_in[1];
    const int*   aamask = (const int*)d_in[2];
    const int*   nbonds = (const int*)d_in[3];
    const float* state  = (const float*)d_in[4];
    const float* grads  = (const float*)d_in[5];
    const float* We    = (const float*)d_in[7];
    const float* be    = (const float*)d_in[8];
    const float* Wq    = (const float*)d_in[9];
    const float* Wk    = (const float*)d_in[10];
    const float* Wv0   = (const float*)d_in[11];
    const float* Wv1   = (const float*)d_in[12];
    const float* Wo0   = (const float*)d_in[13];
    const float* Wself = (const float*)d_in[14];
    const float* b0    = (const float*)d_in[15];

    float* out_xyz   = (float*)d_out;
    float* out_state = out_xyz + MTOT * 3;

    char* ws = (char*)d_ws;
    int*    cnt  = (int*)ws;                              // 16 B
    float4* pact = (float4*)(ws + 16);                    // (MTOT+256)*16 = 151552 B
    int*    idx  = (int*)(ws + 16 + 151552);              // 884736 B

    hipMemsetAsync(cnt, 0, 16, stream);
    k_prep<<<(MTOT * D0_ / 4 + 255) / 256, 256, 0, stream>>>(
        seq, xyz, aamask, (const float4*)state, (float4*)out_state,
        pact, out_xyz, cnt);
    k_nbr<<<(MTOT + WPB - 1) / WPB, 512, 0, stream>>>(pact, cnt, idx);
    k_attn<<<MTOT, 64, 0, stream>>>(xyz, seq, nbonds, state, grads, We, be, Wq, Wk,
                                    Wv0, Wv1, Wo0, Wself, b0, pact, cnt, idx,
                                    out_xyz, out_state);
}